// Round 5
// baseline (326.312 us; speedup 1.0000x reference)
//
#include <hip/hip_runtime.h>

#define D_H 32
#define NREP 32
#define SLOTS 48        // padded CSR slots per node (Poisson(16); P(overflow) ~ 5e-6)
#define BIN_SHIFT 8     // 256 nodes per bin
#define MAXNB 512       // max bins (N <= 131072)
#define BIN_CAP 5120    // capacity per bin region (mean 4096, +16 sigma)
#define SB 256          // bin-role blocks in the fused kernel
#define AB_NPB 128      // nodes per block in projection kernels (2 threads/node)

// ---------------- Fused iteration-0 projection + edge binning ----------------
// Role split by blockIdx: blocks [0, abBlocks) run the ab0 projection; blocks
// [abBlocks, abBlocks+SB) bin edges by dst>>8 (independent work, hides the bin
// pass under the projection).
//
// Projection: thread = (node, half). Each thread computes 16 of the 32 outputs
// (j in [half*16, half*16+16)); f[48] is recomputed by both halves (cheaper
// than a barrier). One-thread-per-node was 14% occupancy / latency-bound
// (1.5 waves/SIMD, 3700-inst serial chain); the split doubles waves and halves
// the chain. Stores go through a transposed LDS tile -> coalesced float4 lines
// (direct row stores measured 4.15x HBM write amplification).

__global__ __launch_bounds__(256) void k_ab0bin(
        const float* __restrict__ x, const float* __restrict__ W_in,
        const float* __restrict__ b_in, const float* __restrict__ W_c,
        const float* __restrict__ b_c, float* __restrict__ A, float* __restrict__ B,
        int N, int abBlocks,
        const int* __restrict__ src, const int* __restrict__ dst,
        int* __restrict__ binCnt, unsigned int* __restrict__ ebuf, int E) {
    __shared__ float st[32][AB_NPB + 1];   // 16.5 KB; also reused as bin histogram
    int tid = threadIdx.x;
    int bid = blockIdx.x;

    if (bid < abBlocks) {
        // ---- projection role ----
        int n0 = bid * AB_NPB;
        int nl = tid & (AB_NPB - 1);
        int half = tid >> 7;               // wave-uniform (256-thread blocks)
        int n = n0 + nl;
        bool act = n < N;
        float f[48];
        float bbr[16];
        if (act) {
            const float4* xr = (const float4*)(x + (size_t)n * 16);
#pragma unroll
            for (int q = 0; q < 4; ++q) {
                float4 v = xr[q];
                f[32 + 4 * q] = v.x; f[33 + 4 * q] = v.y;
                f[34 + 4 * q] = v.z; f[35 + 4 * q] = v.w;
            }
#pragma unroll
            for (int j = 0; j < 32; ++j) {
                const float* w = W_in + j * 16;
                float acc = b_in[j];
#pragma unroll
                for (int i = 0; i < 16; ++i) acc += f[32 + i] * w[i];
                f[j] = tanhf(acc);
            }
#pragma unroll 4
            for (int jj = 0; jj < 16; ++jj) {
                int j = half * 16 + jj;
                const float* w = W_c + j * 96;
                float p = b_c[j];
                float bb = 0.f;
#pragma unroll
                for (int i = 0; i < 48; ++i) {
                    p  += f[i] * w[i];
                    bb += f[i] * w[48 + i];
                }
                st[j][nl] = p - bb;
                bbr[jj] = bb;
            }
        }
        __syncthreads();
        float4* A4 = (float4*)(A + (size_t)n0 * D_H);
#pragma unroll
        for (int k = 0; k < 4; ++k) {
            int i4 = k * 256 + tid;        // 128 nodes * 8 float4
            int nn = i4 >> 3;
            int j0 = (i4 & 7) * 4;
            if (n0 + nn < N) {
                float4 v = {st[j0][nn], st[j0 + 1][nn], st[j0 + 2][nn], st[j0 + 3][nn]};
                A4[i4] = v;
            }
        }
        __syncthreads();
        if (act) {
#pragma unroll
            for (int jj = 0; jj < 16; ++jj) st[half * 16 + jj][nl] = bbr[jj];
        }
        __syncthreads();
        float4* B4 = (float4*)(B + (size_t)n0 * D_H);
#pragma unroll
        for (int k = 0; k < 4; ++k) {
            int i4 = k * 256 + tid;
            int nn = i4 >> 3;
            int j0 = (i4 & 7) * 4;
            if (n0 + nn < N) {
                float4 v = {st[j0][nn], st[j0 + 1][nn], st[j0 + 2][nn], st[j0 + 3][nn]};
                B4[i4] = v;
            }
        }
    } else {
        // ---- bin role: LDS histogram -> one global atomic per (block,bin) ->
        // packed (local_dst<<24 | src) in contiguous per-bin runs ----
        int* hist = (int*)st;
        int b0 = bid - abBlocks;
        for (int i = tid; i < MAXNB; i += 256) hist[i] = 0;
        __syncthreads();
        int chunk = (E + SB - 1) / SB;
        int lo = b0 * chunk;
        int hi = lo + chunk; if (hi > E) hi = E;
        for (int e = lo + tid; e < hi; e += 256) {
            int b = dst[e] >> BIN_SHIFT;
            atomicAdd(&hist[b], 1);
        }
        __syncthreads();
        for (int b = tid; b < MAXNB; b += 256) {
            int c = hist[b];
            int base = c ? atomicAdd(&binCnt[b], c) : 0;
            hist[b] = b * BIN_CAP + base;
        }
        __syncthreads();
        for (int e = lo + tid; e < hi; e += 256) {
            int d = dst[e];
            int s = src[e];
            int b = d >> BIN_SHIFT;
            int pos = atomicAdd(&hist[b], 1);
            if ((unsigned)(pos - b * BIN_CAP) < (unsigned)BIN_CAP)  // overflow guard
                ebuf[pos] = ((unsigned)(d & 255) << 24) | (unsigned)s;
        }
    }
}

// Iteration-1 projection: feats = [H, x], same 2-way j-split + LDS transpose.
__global__ __launch_bounds__(256) void k_ab1(const float* __restrict__ H,
                      const float* __restrict__ x, const float* __restrict__ W_c,
                      const float* __restrict__ b_c, float* __restrict__ A,
                      float* __restrict__ B, int N) {
    __shared__ float st[32][AB_NPB + 1];
    int tid = threadIdx.x;
    int n0 = blockIdx.x * AB_NPB;
    int nl = tid & (AB_NPB - 1);
    int half = tid >> 7;
    int n = n0 + nl;
    bool act = n < N;
    float f[48];
    float bbr[16];
    if (act) {
        const float4* hr = (const float4*)(H + (size_t)n * D_H);
#pragma unroll
        for (int q = 0; q < 8; ++q) {
            float4 v = hr[q];
            f[4 * q]     = v.x; f[4 * q + 1] = v.y;
            f[4 * q + 2] = v.z; f[4 * q + 3] = v.w;
        }
        const float4* xr = (const float4*)(x + (size_t)n * 16);
#pragma unroll
        for (int q = 0; q < 4; ++q) {
            float4 v = xr[q];
            f[32 + 4 * q] = v.x; f[33 + 4 * q] = v.y;
            f[34 + 4 * q] = v.z; f[35 + 4 * q] = v.w;
        }
#pragma unroll 4
        for (int jj = 0; jj < 16; ++jj) {
            int j = half * 16 + jj;
            const float* w = W_c + j * 96;
            float p = b_c[j];
            float bb = 0.f;
#pragma unroll
            for (int i = 0; i < 48; ++i) {
                p  += f[i] * w[i];
                bb += f[i] * w[48 + i];
            }
            st[j][nl] = p - bb;
            bbr[jj] = bb;
        }
    }
    __syncthreads();
    float4* A4 = (float4*)(A + (size_t)n0 * D_H);
#pragma unroll
    for (int k = 0; k < 4; ++k) {
        int i4 = k * 256 + tid;
        int nn = i4 >> 3;
        int j0 = (i4 & 7) * 4;
        if (n0 + nn < N) {
            float4 v = {st[j0][nn], st[j0 + 1][nn], st[j0 + 2][nn], st[j0 + 3][nn]};
            A4[i4] = v;
        }
    }
    __syncthreads();
    if (act) {
#pragma unroll
        for (int jj = 0; jj < 16; ++jj) st[half * 16 + jj][nl] = bbr[jj];
    }
    __syncthreads();
    float4* B4 = (float4*)(B + (size_t)n0 * D_H);
#pragma unroll
    for (int k = 0; k < 4; ++k) {
        int i4 = k * 256 + tid;
        int nn = i4 >> 3;
        int j0 = (i4 & 7) * 4;
        if (n0 + nn < N) {
            float4 v = {st[j0][nn], st[j0 + 1][nn], st[j0 + 2][nn], st[j0 + 3][nn]};
            B4[i4] = v;
        }
    }
}

// CSR step 2: one block owns one bin (256 nodes). Slot counters in LDS (no
// global atomics); cnt doubles as row length.
__global__ __launch_bounds__(256) void k_place(const int* __restrict__ binCnt,
                                               const unsigned int* __restrict__ ebuf,
                                               int* __restrict__ ssrcp,
                                               int* __restrict__ cntG, int N) {
    __shared__ int cnt[256];
    int tid = threadIdx.x;
    int w = blockIdx.x;
    cnt[tid] = 0;
    __syncthreads();
    int n = binCnt[w]; if (n > BIN_CAP) n = BIN_CAP;
    int base = w * BIN_CAP;
    for (int j = tid; j < n; j += 256) {
        unsigned int v = ebuf[base + j];
        int ld = v >> 24;
        int s = v & 0xFFFFFF;
        int slot = atomicAdd(&cnt[ld], 1);
        if (slot < SLOTS)
            ssrcp[(size_t)((w << BIN_SHIFT) + ld) * SLOTS + slot] = s;
    }
    __syncthreads();
    int node = (w << BIN_SHIFT) + tid;
    if (node < N) cntG[node] = cnt[tid] < SLOTS ? cnt[tid] : SLOTS;
}

// ---------- Gather-only edge passes (no atomics in the hot loop) ----------
// 32 lanes per node: lane = 8*s + q. Edge-slot s (0..3) processes slots
// j = s, s+4, ...; quad q (0..7) covers float4 q of the 32-float row.
// Per edge: 8 lanes x dwordx4. Epilogue: shfl_xor(8,16) sums the 4 edge-slots.

__global__ void k_gather1(const int* __restrict__ cntG, const int* __restrict__ ssrcp,
                          const float* __restrict__ A, const float* __restrict__ B,
                          float* __restrict__ H, int N) {
    int t = blockIdx.x * blockDim.x + threadIdx.x;
    int d = t >> 5;
    if (d >= N) return;
    int l = t & 31;
    int q = l & 7;
    int s = l >> 3;
    int len = cntG[d];
    const int* base = ssrcp + (size_t)d * SLOTS;
    float4 a4 = ((const float4*)(A + (size_t)d * D_H))[q];
    float4 acc = {0.f, 0.f, 0.f, 0.f};
    int j = s;
    for (; j + 4 < len; j += 8) {
        int s0 = base[j], s1 = base[j + 4];
        float4 b0 = ((const float4*)(B + (size_t)s0 * D_H))[q];
        float4 b1 = ((const float4*)(B + (size_t)s1 * D_H))[q];
        acc.x += 1.f / (1.f + __expf(-(a4.x + b0.x)));
        acc.y += 1.f / (1.f + __expf(-(a4.y + b0.y)));
        acc.z += 1.f / (1.f + __expf(-(a4.z + b0.z)));
        acc.w += 1.f / (1.f + __expf(-(a4.w + b0.w)));
        acc.x += 1.f / (1.f + __expf(-(a4.x + b1.x)));
        acc.y += 1.f / (1.f + __expf(-(a4.y + b1.y)));
        acc.z += 1.f / (1.f + __expf(-(a4.z + b1.z)));
        acc.w += 1.f / (1.f + __expf(-(a4.w + b1.w)));
    }
    if (j < len) {
        int s0 = base[j];
        float4 b0 = ((const float4*)(B + (size_t)s0 * D_H))[q];
        acc.x += 1.f / (1.f + __expf(-(a4.x + b0.x)));
        acc.y += 1.f / (1.f + __expf(-(a4.y + b0.y)));
        acc.z += 1.f / (1.f + __expf(-(a4.z + b0.z)));
        acc.w += 1.f / (1.f + __expf(-(a4.w + b0.w)));
    }
    acc.x += __shfl_xor(acc.x, 8);  acc.y += __shfl_xor(acc.y, 8);
    acc.z += __shfl_xor(acc.z, 8);  acc.w += __shfl_xor(acc.w, 8);
    acc.x += __shfl_xor(acc.x, 16); acc.y += __shfl_xor(acc.y, 16);
    acc.z += __shfl_xor(acc.z, 16); acc.w += __shfl_xor(acc.w, 16);
    if (s == 0) ((float4*)(H + (size_t)d * D_H))[q] = acc;
}

// Iter 1 fused with the global mean: per-lane float4 accumulation, shfl + LDS
// reduction, replicated atomic lines.
__global__ void k_gather2(const int* __restrict__ cntG, const int* __restrict__ ssrcp,
                          const float* __restrict__ A, const float* __restrict__ B,
                          float* __restrict__ Srep, int N) {
    int l = threadIdx.x & 31;
    int slot = threadIdx.x >> 5;          // 0..7
    int q = l & 7;
    int s = l >> 3;
    int d = blockIdx.x * 8 + slot;
    float4 acc = {0.f, 0.f, 0.f, 0.f};
    if (d < N) {
        int len = cntG[d];
        const int* base = ssrcp + (size_t)d * SLOTS;
        float4 a4 = ((const float4*)(A + (size_t)d * D_H))[q];
        int j = s;
        for (; j + 4 < len; j += 8) {
            int s0 = base[j], s1 = base[j + 4];
            float4 b0 = ((const float4*)(B + (size_t)s0 * D_H))[q];
            float4 b1 = ((const float4*)(B + (size_t)s1 * D_H))[q];
            acc.x += 1.f / (1.f + __expf(-(a4.x + b0.x)));
            acc.y += 1.f / (1.f + __expf(-(a4.y + b0.y)));
            acc.z += 1.f / (1.f + __expf(-(a4.z + b0.z)));
            acc.w += 1.f / (1.f + __expf(-(a4.w + b0.w)));
            acc.x += 1.f / (1.f + __expf(-(a4.x + b1.x)));
            acc.y += 1.f / (1.f + __expf(-(a4.y + b1.y)));
            acc.z += 1.f / (1.f + __expf(-(a4.z + b1.z)));
            acc.w += 1.f / (1.f + __expf(-(a4.w + b1.w)));
        }
        if (j < len) {
            int s0 = base[j];
            float4 b0 = ((const float4*)(B + (size_t)s0 * D_H))[q];
            acc.x += 1.f / (1.f + __expf(-(a4.x + b0.x)));
            acc.y += 1.f / (1.f + __expf(-(a4.y + b0.y)));
            acc.z += 1.f / (1.f + __expf(-(a4.z + b0.z)));
            acc.w += 1.f / (1.f + __expf(-(a4.w + b0.w)));
        }
    }
    acc.x += __shfl_xor(acc.x, 8);  acc.y += __shfl_xor(acc.y, 8);
    acc.z += __shfl_xor(acc.z, 8);  acc.w += __shfl_xor(acc.w, 8);
    acc.x += __shfl_xor(acc.x, 16); acc.y += __shfl_xor(acc.y, 16);
    acc.z += __shfl_xor(acc.z, 16); acc.w += __shfl_xor(acc.w, 16);
    __shared__ float red[8][32];
    if (s == 0) {
        red[slot][4 * q + 0] = acc.x;
        red[slot][4 * q + 1] = acc.y;
        red[slot][4 * q + 2] = acc.z;
        red[slot][4 * q + 3] = acc.w;
    }
    __syncthreads();
    if (threadIdx.x < 32) {
        float sm = 0.f;
#pragma unroll
        for (int r = 0; r < 8; ++r) sm += red[r][threadIdx.x];
        unsafeAtomicAdd(&Srep[(blockIdx.x & (NREP - 1)) * D_H + threadIdx.x], sm);
    }
}

// out = sigmoid(W_out . (S/N) + b_out), S = sum over replicas.
__global__ void k_final(const float* __restrict__ Srep, const float* __restrict__ W_out,
                        const float* __restrict__ b_out, float* __restrict__ out,
                        float invN) {
    int j = threadIdx.x;  // 0..63
    float v = 0.f;
    if (j < 32) {
        float s = 0.f;
#pragma unroll
        for (int r = 0; r < NREP; ++r) s += Srep[r * D_H + j];
        v = s * invN * W_out[j];
    }
#pragma unroll
    for (int off = 32; off > 0; off >>= 1) v += __shfl_down(v, off);
    if (j == 0) out[0] = 1.f / (1.f + __expf(-(v + b_out[0])));
}

extern "C" void kernel_launch(void* const* d_in, const int* in_sizes, int n_in,
                              void* d_out, int out_size, void* d_ws, size_t ws_size,
                              hipStream_t stream) {
    const float* x     = (const float*)d_in[0];
    const int*   ei    = (const int*)d_in[1];
    const float* W_in  = (const float*)d_in[2];
    const float* b_in  = (const float*)d_in[3];
    const float* W_c   = (const float*)d_in[4];
    const float* b_c   = (const float*)d_in[5];
    const float* W_out = (const float*)d_in[6];
    const float* b_out = (const float*)d_in[7];

    const int N = in_sizes[0] / 16;
    const int E = in_sizes[1] / 2;
    const int* src = ei;        // edge_index[0]
    const int* dst = ei + E;    // edge_index[1]

    const int NB = (N + 255) >> BIN_SHIFT;   // 391 for N=100000

    float* H    = (float*)d_ws;                  // N*32
    float* A    = H + (size_t)N * D_H;           // N*32
    float* B    = A + (size_t)N * D_H;           // N*32
    float* Srep = B + (size_t)N * D_H;           // NREP*32
    int*   cntG   = (int*)(Srep + NREP * D_H);   // N
    int*   binCnt = cntG + N;                    // NB (<= MAXNB)
    int*   ssrcp  = binCnt + MAXNB;              // N*SLOTS
    unsigned int* ebuf = (unsigned int*)H;       // NB*BIN_CAP (8MB) overlays H:
                                                 // H is dead until k_gather1, ebuf
                                                 // dead after k_place.

    float* out = (float*)d_out;

    const int abBlocks = (N + AB_NPB - 1) / AB_NPB;   // 782

    // Fused: iteration-0 projection + edge binning (independent work)
    hipMemsetAsync(binCnt, 0, MAXNB * sizeof(int), stream);
    k_ab0bin<<<abBlocks + SB, 256, 0, stream>>>(x, W_in, b_in, W_c, b_c, A, B,
                                                N, abBlocks, src, dst, binCnt, ebuf, E);
    k_place<<<NB, 256, 0, stream>>>(binCnt, ebuf, ssrcp, cntG, N);

    // Iteration 0 edge pass
    k_gather1<<<(int)(((size_t)N * 32 + 255) / 256), 256, 0, stream>>>(cntG, ssrcp, A, B, H, N);

    // Iteration 1 projection, then fused edge+mean reduction
    k_ab1<<<abBlocks, 256, 0, stream>>>(H, x, W_c, b_c, A, B, N);
    hipMemsetAsync(Srep, 0, NREP * D_H * sizeof(float), stream);
    k_gather2<<<(N + 7) / 8, 256, 0, stream>>>(cntG, ssrcp, A, B, Srep, N);

    k_final<<<1, 64, 0, stream>>>(Srep, W_out, b_out, out, 1.f / (float)N);
}

// Round 6
// 291.938 us; speedup vs baseline: 1.1177x; 1.1177x over previous
//
#include <hip/hip_runtime.h>

#define D_H 32
#define NREP 32
#define SLOTS 48        // padded CSR slots per node (Poisson(16); P(overflow) ~ 5e-6)
#define BIN_SHIFT 8     // 256 nodes per bin
#define MAXNB 512       // max bins (N <= 131072)
#define BIN_CAP 5120    // capacity per bin region (mean 4096, +16 sigma)
#define SB 256          // blocks for k_bin
#define NPB 64          // nodes per projection block (4 threads/node, 256 threads)

// ---------------- Projection kernels ----------------
// Thread = (node nl, quarter qq = tid>>6, wave-uniform). Each thread computes 8
// of the 32 A/B output rows. All shared per-node state (x, H) lives in an LDS
// tile with odd stride 65 (worst case 2-way bank conflict = free on CDNA4), so
// nothing is recomputed across quarters. One-thread-per-node was latency-bound
// (14% occupancy, VALUBusy 20%, 3600-op serial chain); this quarters the chain
// and x4 the wave count. Outputs are staged transposed in LDS and flushed as
// coalesced float4 lines (direct row stores measured 4.15x write amplification).

__device__ __forceinline__ void conv_and_flush(
        float st[48][NPB + 1], const float* __restrict__ W_c,
        const float* __restrict__ b_c, float* __restrict__ A, float* __restrict__ B,
        int N, int n0, int tid, int nl, int qq) {
    // f[0..47] -> registers (rows 0..31 = H, 32..47 = x)
    float f[48];
#pragma unroll
    for (int i = 0; i < 48; ++i) f[i] = st[i][nl];
    float pr[8], br[8];
#pragma unroll 2
    for (int jj = 0; jj < 8; ++jj) {
        int j = qq * 8 + jj;                 // wave-uniform -> scalar weight loads
        const float* w = W_c + j * 96;
        float p = b_c[j];
        float bb = 0.f;
#pragma unroll
        for (int i = 0; i < 48; ++i) {
            p  += f[i] * w[i];
            bb += f[i] * w[48 + i];
        }
        pr[jj] = p - bb;                     // A value
        br[jj] = bb;                         // B value
    }
    __syncthreads();                         // all f reads done -> reuse LDS
#pragma unroll
    for (int jj = 0; jj < 8; ++jj) st[qq * 8 + jj][nl] = pr[jj];
    __syncthreads();
    float4* A4 = (float4*)(A + (size_t)n0 * D_H);
#pragma unroll
    for (int k = 0; k < 2; ++k) {
        int i4 = k * 256 + tid;              // 64 nodes * 8 float4
        int nn = i4 >> 3;
        int j0 = (i4 & 7) * 4;
        if (n0 + nn < N) {
            float4 v = {st[j0][nn], st[j0 + 1][nn], st[j0 + 2][nn], st[j0 + 3][nn]};
            A4[i4] = v;
        }
    }
    __syncthreads();
#pragma unroll
    for (int jj = 0; jj < 8; ++jj) st[qq * 8 + jj][nl] = br[jj];
    __syncthreads();
    float4* B4 = (float4*)(B + (size_t)n0 * D_H);
#pragma unroll
    for (int k = 0; k < 2; ++k) {
        int i4 = k * 256 + tid;
        int nn = i4 >> 3;
        int j0 = (i4 & 7) * 4;
        if (n0 + nn < N) {
            float4 v = {st[j0][nn], st[j0 + 1][nn], st[j0 + 2][nn], st[j0 + 3][nn]};
            B4[i4] = v;
        }
    }
}

__global__ __launch_bounds__(256) void k_ab0(const float* __restrict__ x,
                      const float* __restrict__ W_in, const float* __restrict__ b_in,
                      const float* __restrict__ W_c, const float* __restrict__ b_c,
                      float* __restrict__ A, float* __restrict__ B, int N) {
    __shared__ float st[48][NPB + 1];        // 12.5 KB
    int tid = threadIdx.x;
    int n0 = blockIdx.x * NPB;
    int nl = tid & (NPB - 1);
    int qq = tid >> 6;
    // stage x coalesced: 64 rows * 4 float4, thread i -> row i>>2, chunk i&3
    {
        int row = tid >> 2, c = tid & 3;
        float4 v = {0.f, 0.f, 0.f, 0.f};
        if (n0 + row < N) v = ((const float4*)(x + (size_t)(n0 + row) * 16))[c];
        st[32 + 4 * c + 0][row] = v.x;
        st[32 + 4 * c + 1][row] = v.y;
        st[32 + 4 * c + 2][row] = v.z;
        st[32 + 4 * c + 3][row] = v.w;
    }
    __syncthreads();
    // input-net: each quarter computes 8 tanh rows for its node
    {
        float xf[16];
#pragma unroll
        for (int i = 0; i < 16; ++i) xf[i] = st[32 + i][nl];
#pragma unroll
        for (int jj = 0; jj < 8; ++jj) {
            int j = qq * 8 + jj;
            const float* w = W_in + j * 16;
            float acc = b_in[j];
#pragma unroll
            for (int i = 0; i < 16; ++i) acc += xf[i] * w[i];
            st[j][nl] = tanhf(acc);
        }
    }
    __syncthreads();
    conv_and_flush(st, W_c, b_c, A, B, N, n0, tid, nl, qq);
}

__global__ __launch_bounds__(256) void k_ab1(const float* __restrict__ H,
                      const float* __restrict__ x, const float* __restrict__ W_c,
                      const float* __restrict__ b_c, float* __restrict__ A,
                      float* __restrict__ B, int N) {
    __shared__ float st[48][NPB + 1];
    int tid = threadIdx.x;
    int n0 = blockIdx.x * NPB;
    int nl = tid & (NPB - 1);
    int qq = tid >> 6;
    // stage H coalesced: 64 rows * 8 float4
#pragma unroll
    for (int k = 0; k < 2; ++k) {
        int i = k * 256 + tid;
        int row = i >> 3, c = i & 7;
        float4 v = {0.f, 0.f, 0.f, 0.f};
        if (n0 + row < N) v = ((const float4*)(H + (size_t)(n0 + row) * D_H))[c];
        st[4 * c + 0][row] = v.x;
        st[4 * c + 1][row] = v.y;
        st[4 * c + 2][row] = v.z;
        st[4 * c + 3][row] = v.w;
    }
    // stage x coalesced
    {
        int row = tid >> 2, c = tid & 3;
        float4 v = {0.f, 0.f, 0.f, 0.f};
        if (n0 + row < N) v = ((const float4*)(x + (size_t)(n0 + row) * 16))[c];
        st[32 + 4 * c + 0][row] = v.x;
        st[32 + 4 * c + 1][row] = v.y;
        st[32 + 4 * c + 2][row] = v.z;
        st[32 + 4 * c + 3][row] = v.w;
    }
    __syncthreads();
    conv_and_flush(st, W_c, b_c, A, B, N, n0, tid, nl, qq);
}

// ---------- CSR build, atomic-light ----------
// Step 1: bin edges by dst>>8. Per-block LDS histogram -> one global atomic per
// (block,bin) to reserve space -> packed (local_dst<<24 | src) in contiguous
// per-bin runs. ebuf region for bin b: [b*BIN_CAP, (b+1)*BIN_CAP).
__global__ __launch_bounds__(256) void k_bin(const int* __restrict__ src,
                                             const int* __restrict__ dst,
                                             int* __restrict__ binCnt,
                                             unsigned int* __restrict__ ebuf, int E) {
    __shared__ int hist[MAXNB];
    int tid = threadIdx.x;
    for (int i = tid; i < MAXNB; i += 256) hist[i] = 0;
    __syncthreads();
    int chunk = (E + SB - 1) / SB;
    int lo = blockIdx.x * chunk;
    int hi = lo + chunk; if (hi > E) hi = E;
    for (int e = lo + tid; e < hi; e += 256) {
        int b = dst[e] >> BIN_SHIFT;
        atomicAdd(&hist[b], 1);
    }
    __syncthreads();
    for (int b = tid; b < MAXNB; b += 256) {
        int c = hist[b];
        int base = c ? atomicAdd(&binCnt[b], c) : 0;
        hist[b] = b * BIN_CAP + base;
    }
    __syncthreads();
    for (int e = lo + tid; e < hi; e += 256) {
        int d = dst[e];
        int s = src[e];
        int b = d >> BIN_SHIFT;
        int pos = atomicAdd(&hist[b], 1);
        if ((unsigned)(pos - b * BIN_CAP) < (unsigned)BIN_CAP)  // overflow guard
            ebuf[pos] = ((unsigned)(d & 255) << 24) | (unsigned)s;
    }
}

// Step 2: one block owns one bin (256 nodes). Slot counters in LDS (no global
// atomics); cnt doubles as row length.
__global__ __launch_bounds__(256) void k_place(const int* __restrict__ binCnt,
                                               const unsigned int* __restrict__ ebuf,
                                               int* __restrict__ ssrcp,
                                               int* __restrict__ cntG, int N) {
    __shared__ int cnt[256];
    int tid = threadIdx.x;
    int w = blockIdx.x;
    cnt[tid] = 0;
    __syncthreads();
    int n = binCnt[w]; if (n > BIN_CAP) n = BIN_CAP;
    int base = w * BIN_CAP;
    for (int j = tid; j < n; j += 256) {
        unsigned int v = ebuf[base + j];
        int ld = v >> 24;
        int s = v & 0xFFFFFF;
        int slot = atomicAdd(&cnt[ld], 1);
        if (slot < SLOTS)
            ssrcp[(size_t)((w << BIN_SHIFT) + ld) * SLOTS + slot] = s;
    }
    __syncthreads();
    int node = (w << BIN_SHIFT) + tid;
    if (node < N) cntG[node] = cnt[tid] < SLOTS ? cnt[tid] : SLOTS;
}

// ---------- Gather-only edge passes (no atomics in the hot loop) ----------
// 32 lanes per node: lane = 8*s + q. Edge-slot s (0..3) processes slots
// j = s, s+4, ...; quad q (0..7) covers float4 q of the 32-float row.
// Per edge: 8 lanes x dwordx4. Epilogue: shfl_xor(8,16) sums the 4 edge-slots.

__global__ void k_gather1(const int* __restrict__ cntG, const int* __restrict__ ssrcp,
                          const float* __restrict__ A, const float* __restrict__ B,
                          float* __restrict__ H, int N) {
    int t = blockIdx.x * blockDim.x + threadIdx.x;
    int d = t >> 5;
    if (d >= N) return;
    int l = t & 31;
    int q = l & 7;
    int s = l >> 3;
    int len = cntG[d];
    const int* base = ssrcp + (size_t)d * SLOTS;
    float4 a4 = ((const float4*)(A + (size_t)d * D_H))[q];
    float4 acc = {0.f, 0.f, 0.f, 0.f};
    int j = s;
    for (; j + 4 < len; j += 8) {
        int s0 = base[j], s1 = base[j + 4];
        float4 b0 = ((const float4*)(B + (size_t)s0 * D_H))[q];
        float4 b1 = ((const float4*)(B + (size_t)s1 * D_H))[q];
        acc.x += 1.f / (1.f + __expf(-(a4.x + b0.x)));
        acc.y += 1.f / (1.f + __expf(-(a4.y + b0.y)));
        acc.z += 1.f / (1.f + __expf(-(a4.z + b0.z)));
        acc.w += 1.f / (1.f + __expf(-(a4.w + b0.w)));
        acc.x += 1.f / (1.f + __expf(-(a4.x + b1.x)));
        acc.y += 1.f / (1.f + __expf(-(a4.y + b1.y)));
        acc.z += 1.f / (1.f + __expf(-(a4.z + b1.z)));
        acc.w += 1.f / (1.f + __expf(-(a4.w + b1.w)));
    }
    if (j < len) {
        int s0 = base[j];
        float4 b0 = ((const float4*)(B + (size_t)s0 * D_H))[q];
        acc.x += 1.f / (1.f + __expf(-(a4.x + b0.x)));
        acc.y += 1.f / (1.f + __expf(-(a4.y + b0.y)));
        acc.z += 1.f / (1.f + __expf(-(a4.z + b0.z)));
        acc.w += 1.f / (1.f + __expf(-(a4.w + b0.w)));
    }
    acc.x += __shfl_xor(acc.x, 8);  acc.y += __shfl_xor(acc.y, 8);
    acc.z += __shfl_xor(acc.z, 8);  acc.w += __shfl_xor(acc.w, 8);
    acc.x += __shfl_xor(acc.x, 16); acc.y += __shfl_xor(acc.y, 16);
    acc.z += __shfl_xor(acc.z, 16); acc.w += __shfl_xor(acc.w, 16);
    if (s == 0) ((float4*)(H + (size_t)d * D_H))[q] = acc;
}

// Iter 1 fused with the global mean: per-lane float4 accumulation, shfl + LDS
// reduction, replicated atomic lines.
__global__ void k_gather2(const int* __restrict__ cntG, const int* __restrict__ ssrcp,
                          const float* __restrict__ A, const float* __restrict__ B,
                          float* __restrict__ Srep, int N) {
    int l = threadIdx.x & 31;
    int slot = threadIdx.x >> 5;          // 0..7
    int q = l & 7;
    int s = l >> 3;
    int d = blockIdx.x * 8 + slot;
    float4 acc = {0.f, 0.f, 0.f, 0.f};
    if (d < N) {
        int len = cntG[d];
        const int* base = ssrcp + (size_t)d * SLOTS;
        float4 a4 = ((const float4*)(A + (size_t)d * D_H))[q];
        int j = s;
        for (; j + 4 < len; j += 8) {
            int s0 = base[j], s1 = base[j + 4];
            float4 b0 = ((const float4*)(B + (size_t)s0 * D_H))[q];
            float4 b1 = ((const float4*)(B + (size_t)s1 * D_H))[q];
            acc.x += 1.f / (1.f + __expf(-(a4.x + b0.x)));
            acc.y += 1.f / (1.f + __expf(-(a4.y + b0.y)));
            acc.z += 1.f / (1.f + __expf(-(a4.z + b0.z)));
            acc.w += 1.f / (1.f + __expf(-(a4.w + b0.w)));
            acc.x += 1.f / (1.f + __expf(-(a4.x + b1.x)));
            acc.y += 1.f / (1.f + __expf(-(a4.y + b1.y)));
            acc.z += 1.f / (1.f + __expf(-(a4.z + b1.z)));
            acc.w += 1.f / (1.f + __expf(-(a4.w + b1.w)));
        }
        if (j < len) {
            int s0 = base[j];
            float4 b0 = ((const float4*)(B + (size_t)s0 * D_H))[q];
            acc.x += 1.f / (1.f + __expf(-(a4.x + b0.x)));
            acc.y += 1.f / (1.f + __expf(-(a4.y + b0.y)));
            acc.z += 1.f / (1.f + __expf(-(a4.z + b0.z)));
            acc.w += 1.f / (1.f + __expf(-(a4.w + b0.w)));
        }
    }
    acc.x += __shfl_xor(acc.x, 8);  acc.y += __shfl_xor(acc.y, 8);
    acc.z += __shfl_xor(acc.z, 8);  acc.w += __shfl_xor(acc.w, 8);
    acc.x += __shfl_xor(acc.x, 16); acc.y += __shfl_xor(acc.y, 16);
    acc.z += __shfl_xor(acc.z, 16); acc.w += __shfl_xor(acc.w, 16);
    __shared__ float red[8][32];
    if (s == 0) {
        red[slot][4 * q + 0] = acc.x;
        red[slot][4 * q + 1] = acc.y;
        red[slot][4 * q + 2] = acc.z;
        red[slot][4 * q + 3] = acc.w;
    }
    __syncthreads();
    if (threadIdx.x < 32) {
        float sm = 0.f;
#pragma unroll
        for (int r = 0; r < 8; ++r) sm += red[r][threadIdx.x];
        unsafeAtomicAdd(&Srep[(blockIdx.x & (NREP - 1)) * D_H + threadIdx.x], sm);
    }
}

// out = sigmoid(W_out . (S/N) + b_out), S = sum over replicas.
__global__ void k_final(const float* __restrict__ Srep, const float* __restrict__ W_out,
                        const float* __restrict__ b_out, float* __restrict__ out,
                        float invN) {
    int j = threadIdx.x;  // 0..63
    float v = 0.f;
    if (j < 32) {
        float s = 0.f;
#pragma unroll
        for (int r = 0; r < NREP; ++r) s += Srep[r * D_H + j];
        v = s * invN * W_out[j];
    }
#pragma unroll
    for (int off = 32; off > 0; off >>= 1) v += __shfl_down(v, off);
    if (j == 0) out[0] = 1.f / (1.f + __expf(-(v + b_out[0])));
}

extern "C" void kernel_launch(void* const* d_in, const int* in_sizes, int n_in,
                              void* d_out, int out_size, void* d_ws, size_t ws_size,
                              hipStream_t stream) {
    const float* x     = (const float*)d_in[0];
    const int*   ei    = (const int*)d_in[1];
    const float* W_in  = (const float*)d_in[2];
    const float* b_in  = (const float*)d_in[3];
    const float* W_c   = (const float*)d_in[4];
    const float* b_c   = (const float*)d_in[5];
    const float* W_out = (const float*)d_in[6];
    const float* b_out = (const float*)d_in[7];

    const int N = in_sizes[0] / 16;
    const int E = in_sizes[1] / 2;
    const int* src = ei;        // edge_index[0]
    const int* dst = ei + E;    // edge_index[1]

    const int NB = (N + 255) >> BIN_SHIFT;   // 391 for N=100000

    float* H    = (float*)d_ws;                  // N*32
    float* A    = H + (size_t)N * D_H;           // N*32
    float* B    = A + (size_t)N * D_H;           // N*32
    float* Srep = B + (size_t)N * D_H;           // NREP*32
    int*   cntG   = (int*)(Srep + NREP * D_H);   // N
    int*   binCnt = cntG + N;                    // NB (<= MAXNB)
    int*   ssrcp  = binCnt + MAXNB;              // N*SLOTS
    unsigned int* ebuf = (unsigned int*)H;       // NB*BIN_CAP (8MB) overlays H:
                                                 // H dead until k_gather1, ebuf
                                                 // dead after k_place.

    float* out = (float*)d_out;

    const int abBlocks = (N + NPB - 1) / NPB;    // 1563

    // CSR build (reused by both iterations)
    hipMemsetAsync(binCnt, 0, MAXNB * sizeof(int), stream);
    k_bin<<<SB, 256, 0, stream>>>(src, dst, binCnt, ebuf, E);
    k_place<<<NB, 256, 0, stream>>>(binCnt, ebuf, ssrcp, cntG, N);

    // Iteration 0
    k_ab0<<<abBlocks, 256, 0, stream>>>(x, W_in, b_in, W_c, b_c, A, B, N);
    k_gather1<<<(int)(((size_t)N * 32 + 255) / 256), 256, 0, stream>>>(cntG, ssrcp, A, B, H, N);

    // Iteration 1
    k_ab1<<<abBlocks, 256, 0, stream>>>(H, x, W_c, b_c, A, B, N);
    hipMemsetAsync(Srep, 0, NREP * D_H * sizeof(float), stream);
    k_gather2<<<(N + 7) / 8, 256, 0, stream>>>(cntG, ssrcp, A, B, Srep, N);

    k_final<<<1, 64, 0, stream>>>(Srep, W_out, b_out, out, 1.f / (float)N);
}

// Round 7
// 251.580 us; speedup vs baseline: 1.2971x; 1.1604x over previous
//
#include <hip/hip_runtime.h>

#define D_H 32
#define NREP 32
#define SLOTS 48        // padded CSR slots per node (Poisson(16); P(overflow) ~ 5e-6)
#define BIN_SHIFT 8     // 256 nodes per bin
#define MAXNB 512       // max bins (N <= 131072)
#define BIN_CAP 5120    // capacity per bin region (mean 4096, +16 sigma)
#define SB 256          // blocks for k_bin
#define PNPB 64         // nodes per projection block
#define SF 52           // f-tile stride (mult of 4 -> 16B-aligned float4 slots)

// ---------------- Projection kernels ----------------
// Mapping: thread = (node-slot, output-column j = tid&31). Lane j computes
// A[n][j], B[n][j] directly, so a half-wave's 32 dword stores form one
// contiguous 128B line: coalesced, no LDS-transpose epilogue (round-4/6
// versions burned 3 barriers + a transpose on this). Weights are per-lane
// REGISTER-resident (W_c row j = 96 VGPR, loaded once per block from the
// L1-resident 12KB table, amortized over 64 nodes). f[48] is read from the
// LDS tile via broadcast ds_read_b128 (32 j-lanes read the same address ->
// hardware broadcast; 2 node-slots per wave -> 2-way, free). Per-thread serial
// chain ~96 FMA per node-pair vs ~900 in the row-mapped version; 32 threads
// per node gives 8x the TLP of round 6 (which sat at 24% occupancy, 28% VALU).

__global__ __launch_bounds__(256) void k_ab0(const float* __restrict__ x,
                      const float* __restrict__ W_in, const float* __restrict__ b_in,
                      const float* __restrict__ W_c, const float* __restrict__ b_c,
                      float* __restrict__ A, float* __restrict__ B, int N) {
    __shared__ float f[PNPB][SF];            // [node][0..31=H0, 32..47=x], 13.3 KB
    int tid = threadIdx.x;
    int n0 = blockIdx.x * PNPB;
    int wv = tid >> 6;                       // wave 0..3
    int h  = (tid >> 5) & 1;                 // node-slot within wave
    int j  = tid & 31;                       // output column
    // per-lane weights -> registers
    float wc[96];
    {
        const float4* wr = (const float4*)(W_c + j * 96);
#pragma unroll
        for (int q = 0; q < 24; ++q) {
            float4 v = wr[q];
            wc[4 * q] = v.x; wc[4 * q + 1] = v.y; wc[4 * q + 2] = v.z; wc[4 * q + 3] = v.w;
        }
    }
    float win[16];
    {
        const float4* wr = (const float4*)(W_in + j * 16);
#pragma unroll
        for (int q = 0; q < 4; ++q) {
            float4 v = wr[q];
            win[4 * q] = v.x; win[4 * q + 1] = v.y; win[4 * q + 2] = v.z; win[4 * q + 3] = v.w;
        }
    }
    float bc = b_c[j];
    float bi = b_in[j];
    // stage x coalesced: row = tid>>2 (0..63), chunk c = tid&3
    {
        int row = tid >> 2, c = tid & 3;
        float4 v = {0.f, 0.f, 0.f, 0.f};
        if (n0 + row < N) v = ((const float4*)(x + (size_t)(n0 + row) * 16))[c];
        *(float4*)&f[row][32 + 4 * c] = v;
    }
    __syncthreads();
    // input-net + conv, wave-local nodes [wv*16, wv*16+16), pair per iteration.
    // No barrier needed: each wave only touches its own 16 rows, and intra-wave
    // ds_write -> ds_read ordering is enforced by lgkmcnt.
#pragma unroll 2
    for (int it = 0; it < 8; ++it) {
        int n = wv * 16 + it * 2 + h;        // local node
        // input-net: H0[n][j]
        {
            float4 x0 = *(const float4*)&f[n][32];
            float4 x1 = *(const float4*)&f[n][36];
            float4 x2 = *(const float4*)&f[n][40];
            float4 x3 = *(const float4*)&f[n][44];
            float acc = bi;
            acc += x0.x * win[0] + x0.y * win[1] + x0.z * win[2] + x0.w * win[3];
            acc += x1.x * win[4] + x1.y * win[5] + x1.z * win[6] + x1.w * win[7];
            acc += x2.x * win[8] + x2.y * win[9] + x2.z * win[10] + x2.w * win[11];
            acc += x3.x * win[12] + x3.y * win[13] + x3.z * win[14] + x3.w * win[15];
            f[n][j] = tanhf(acc);
        }
        // conv: p = b + W1.f ; bb = W2.f  (f = [H0, x], 48 values, broadcast reads)
        float p = bc, bb = 0.f;
#pragma unroll
        for (int q = 0; q < 12; ++q) {
            float4 v = *(const float4*)&f[n][4 * q];
            p  += v.x * wc[4 * q]      + v.y * wc[4 * q + 1]
                + v.z * wc[4 * q + 2]  + v.w * wc[4 * q + 3];
            bb += v.x * wc[48 + 4 * q]     + v.y * wc[48 + 4 * q + 1]
                + v.z * wc[48 + 4 * q + 2] + v.w * wc[48 + 4 * q + 3];
        }
        int g = n0 + n;
        if (g < N) {
            A[(size_t)g * D_H + j] = p - bb;
            B[(size_t)g * D_H + j] = bb;
        }
    }
}

__global__ __launch_bounds__(256) void k_ab1(const float* __restrict__ H,
                      const float* __restrict__ x, const float* __restrict__ W_c,
                      const float* __restrict__ b_c, float* __restrict__ A,
                      float* __restrict__ B, int N) {
    __shared__ float f[PNPB][SF];
    int tid = threadIdx.x;
    int n0 = blockIdx.x * PNPB;
    int wv = tid >> 6;
    int h  = (tid >> 5) & 1;
    int j  = tid & 31;
    float wc[96];
    {
        const float4* wr = (const float4*)(W_c + j * 96);
#pragma unroll
        for (int q = 0; q < 24; ++q) {
            float4 v = wr[q];
            wc[4 * q] = v.x; wc[4 * q + 1] = v.y; wc[4 * q + 2] = v.z; wc[4 * q + 3] = v.w;
        }
    }
    float bc = b_c[j];
    // stage H coalesced: 64 rows * 8 float4
#pragma unroll
    for (int k = 0; k < 2; ++k) {
        int i = k * 256 + tid;
        int row = i >> 3, c = i & 7;
        float4 v = {0.f, 0.f, 0.f, 0.f};
        if (n0 + row < N) v = ((const float4*)(H + (size_t)(n0 + row) * D_H))[c];
        *(float4*)&f[row][4 * c] = v;
    }
    // stage x coalesced
    {
        int row = tid >> 2, c = tid & 3;
        float4 v = {0.f, 0.f, 0.f, 0.f};
        if (n0 + row < N) v = ((const float4*)(x + (size_t)(n0 + row) * 16))[c];
        *(float4*)&f[row][32 + 4 * c] = v;
    }
    __syncthreads();
#pragma unroll 2
    for (int it = 0; it < 8; ++it) {
        int n = wv * 16 + it * 2 + h;
        float p = bc, bb = 0.f;
#pragma unroll
        for (int q = 0; q < 12; ++q) {
            float4 v = *(const float4*)&f[n][4 * q];
            p  += v.x * wc[4 * q]      + v.y * wc[4 * q + 1]
                + v.z * wc[4 * q + 2]  + v.w * wc[4 * q + 3];
            bb += v.x * wc[48 + 4 * q]     + v.y * wc[48 + 4 * q + 1]
                + v.z * wc[48 + 4 * q + 2] + v.w * wc[48 + 4 * q + 3];
        }
        int g = n0 + n;
        if (g < N) {
            A[(size_t)g * D_H + j] = p - bb;
            B[(size_t)g * D_H + j] = bb;
        }
    }
}

// ---------- CSR build, atomic-light ----------
// Step 1: bin edges by dst>>8. Per-block LDS histogram -> one global atomic per
// (block,bin) to reserve space -> packed (local_dst<<24 | src) in contiguous
// per-bin runs. ebuf region for bin b: [b*BIN_CAP, (b+1)*BIN_CAP).
__global__ __launch_bounds__(256) void k_bin(const int* __restrict__ src,
                                             const int* __restrict__ dst,
                                             int* __restrict__ binCnt,
                                             unsigned int* __restrict__ ebuf, int E) {
    __shared__ int hist[MAXNB];
    int tid = threadIdx.x;
    for (int i = tid; i < MAXNB; i += 256) hist[i] = 0;
    __syncthreads();
    int chunk = (E + SB - 1) / SB;
    int lo = blockIdx.x * chunk;
    int hi = lo + chunk; if (hi > E) hi = E;
    for (int e = lo + tid; e < hi; e += 256) {
        int b = dst[e] >> BIN_SHIFT;
        atomicAdd(&hist[b], 1);
    }
    __syncthreads();
    for (int b = tid; b < MAXNB; b += 256) {
        int c = hist[b];
        int base = c ? atomicAdd(&binCnt[b], c) : 0;
        hist[b] = b * BIN_CAP + base;
    }
    __syncthreads();
    for (int e = lo + tid; e < hi; e += 256) {
        int d = dst[e];
        int s = src[e];
        int b = d >> BIN_SHIFT;
        int pos = atomicAdd(&hist[b], 1);
        if ((unsigned)(pos - b * BIN_CAP) < (unsigned)BIN_CAP)  // overflow guard
            ebuf[pos] = ((unsigned)(d & 255) << 24) | (unsigned)s;
    }
}

// Step 2: one block owns one bin (256 nodes). Slot counters in LDS (no global
// atomics); cnt doubles as row length.
__global__ __launch_bounds__(256) void k_place(const int* __restrict__ binCnt,
                                               const unsigned int* __restrict__ ebuf,
                                               int* __restrict__ ssrcp,
                                               int* __restrict__ cntG, int N) {
    __shared__ int cnt[256];
    int tid = threadIdx.x;
    int w = blockIdx.x;
    cnt[tid] = 0;
    __syncthreads();
    int n = binCnt[w]; if (n > BIN_CAP) n = BIN_CAP;
    int base = w * BIN_CAP;
    for (int j = tid; j < n; j += 256) {
        unsigned int v = ebuf[base + j];
        int ld = v >> 24;
        int s = v & 0xFFFFFF;
        int slot = atomicAdd(&cnt[ld], 1);
        if (slot < SLOTS)
            ssrcp[(size_t)((w << BIN_SHIFT) + ld) * SLOTS + slot] = s;
    }
    __syncthreads();
    int node = (w << BIN_SHIFT) + tid;
    if (node < N) cntG[node] = cnt[tid] < SLOTS ? cnt[tid] : SLOTS;
}

// ---------- Gather-only edge passes (no atomics in the hot loop) ----------
// 32 lanes per node: lane = 8*s + q. Edge-slot s (0..3) processes slots
// j = s, s+4, ...; quad q (0..7) covers float4 q of the 32-float row.
// Per edge: 8 lanes x dwordx4. Epilogue: shfl_xor(8,16) sums the 4 edge-slots.

__global__ void k_gather1(const int* __restrict__ cntG, const int* __restrict__ ssrcp,
                          const float* __restrict__ A, const float* __restrict__ B,
                          float* __restrict__ H, int N) {
    int t = blockIdx.x * blockDim.x + threadIdx.x;
    int d = t >> 5;
    if (d >= N) return;
    int l = t & 31;
    int q = l & 7;
    int s = l >> 3;
    int len = cntG[d];
    const int* base = ssrcp + (size_t)d * SLOTS;
    float4 a4 = ((const float4*)(A + (size_t)d * D_H))[q];
    float4 acc = {0.f, 0.f, 0.f, 0.f};
    int j = s;
    for (; j + 4 < len; j += 8) {
        int s0 = base[j], s1 = base[j + 4];
        float4 b0 = ((const float4*)(B + (size_t)s0 * D_H))[q];
        float4 b1 = ((const float4*)(B + (size_t)s1 * D_H))[q];
        acc.x += 1.f / (1.f + __expf(-(a4.x + b0.x)));
        acc.y += 1.f / (1.f + __expf(-(a4.y + b0.y)));
        acc.z += 1.f / (1.f + __expf(-(a4.z + b0.z)));
        acc.w += 1.f / (1.f + __expf(-(a4.w + b0.w)));
        acc.x += 1.f / (1.f + __expf(-(a4.x + b1.x)));
        acc.y += 1.f / (1.f + __expf(-(a4.y + b1.y)));
        acc.z += 1.f / (1.f + __expf(-(a4.z + b1.z)));
        acc.w += 1.f / (1.f + __expf(-(a4.w + b1.w)));
    }
    if (j < len) {
        int s0 = base[j];
        float4 b0 = ((const float4*)(B + (size_t)s0 * D_H))[q];
        acc.x += 1.f / (1.f + __expf(-(a4.x + b0.x)));
        acc.y += 1.f / (1.f + __expf(-(a4.y + b0.y)));
        acc.z += 1.f / (1.f + __expf(-(a4.z + b0.z)));
        acc.w += 1.f / (1.f + __expf(-(a4.w + b0.w)));
    }
    acc.x += __shfl_xor(acc.x, 8);  acc.y += __shfl_xor(acc.y, 8);
    acc.z += __shfl_xor(acc.z, 8);  acc.w += __shfl_xor(acc.w, 8);
    acc.x += __shfl_xor(acc.x, 16); acc.y += __shfl_xor(acc.y, 16);
    acc.z += __shfl_xor(acc.z, 16); acc.w += __shfl_xor(acc.w, 16);
    if (s == 0) ((float4*)(H + (size_t)d * D_H))[q] = acc;
}

// Iter 1 fused with the global mean: per-lane float4 accumulation, shfl + LDS
// reduction, replicated atomic lines.
__global__ void k_gather2(const int* __restrict__ cntG, const int* __restrict__ ssrcp,
                          const float* __restrict__ A, const float* __restrict__ B,
                          float* __restrict__ Srep, int N) {
    int l = threadIdx.x & 31;
    int slot = threadIdx.x >> 5;          // 0..7
    int q = l & 7;
    int s = l >> 3;
    int d = blockIdx.x * 8 + slot;
    float4 acc = {0.f, 0.f, 0.f, 0.f};
    if (d < N) {
        int len = cntG[d];
        const int* base = ssrcp + (size_t)d * SLOTS;
        float4 a4 = ((const float4*)(A + (size_t)d * D_H))[q];
        int j = s;
        for (; j + 4 < len; j += 8) {
            int s0 = base[j], s1 = base[j + 4];
            float4 b0 = ((const float4*)(B + (size_t)s0 * D_H))[q];
            float4 b1 = ((const float4*)(B + (size_t)s1 * D_H))[q];
            acc.x += 1.f / (1.f + __expf(-(a4.x + b0.x)));
            acc.y += 1.f / (1.f + __expf(-(a4.y + b0.y)));
            acc.z += 1.f / (1.f + __expf(-(a4.z + b0.z)));
            acc.w += 1.f / (1.f + __expf(-(a4.w + b0.w)));
            acc.x += 1.f / (1.f + __expf(-(a4.x + b1.x)));
            acc.y += 1.f / (1.f + __expf(-(a4.y + b1.y)));
            acc.z += 1.f / (1.f + __expf(-(a4.z + b1.z)));
            acc.w += 1.f / (1.f + __expf(-(a4.w + b1.w)));
        }
        if (j < len) {
            int s0 = base[j];
            float4 b0 = ((const float4*)(B + (size_t)s0 * D_H))[q];
            acc.x += 1.f / (1.f + __expf(-(a4.x + b0.x)));
            acc.y += 1.f / (1.f + __expf(-(a4.y + b0.y)));
            acc.z += 1.f / (1.f + __expf(-(a4.z + b0.z)));
            acc.w += 1.f / (1.f + __expf(-(a4.w + b0.w)));
        }
    }
    acc.x += __shfl_xor(acc.x, 8);  acc.y += __shfl_xor(acc.y, 8);
    acc.z += __shfl_xor(acc.z, 8);  acc.w += __shfl_xor(acc.w, 8);
    acc.x += __shfl_xor(acc.x, 16); acc.y += __shfl_xor(acc.y, 16);
    acc.z += __shfl_xor(acc.z, 16); acc.w += __shfl_xor(acc.w, 16);
    __shared__ float red[8][32];
    if (s == 0) {
        red[slot][4 * q + 0] = acc.x;
        red[slot][4 * q + 1] = acc.y;
        red[slot][4 * q + 2] = acc.z;
        red[slot][4 * q + 3] = acc.w;
    }
    __syncthreads();
    if (threadIdx.x < 32) {
        float sm = 0.f;
#pragma unroll
        for (int r = 0; r < 8; ++r) sm += red[r][threadIdx.x];
        unsafeAtomicAdd(&Srep[(blockIdx.x & (NREP - 1)) * D_H + threadIdx.x], sm);
    }
}

// out = sigmoid(W_out . (S/N) + b_out), S = sum over replicas.
__global__ void k_final(const float* __restrict__ Srep, const float* __restrict__ W_out,
                        const float* __restrict__ b_out, float* __restrict__ out,
                        float invN) {
    int j = threadIdx.x;  // 0..63
    float v = 0.f;
    if (j < 32) {
        float s = 0.f;
#pragma unroll
        for (int r = 0; r < NREP; ++r) s += Srep[r * D_H + j];
        v = s * invN * W_out[j];
    }
#pragma unroll
    for (int off = 32; off > 0; off >>= 1) v += __shfl_down(v, off);
    if (j == 0) out[0] = 1.f / (1.f + __expf(-(v + b_out[0])));
}

extern "C" void kernel_launch(void* const* d_in, const int* in_sizes, int n_in,
                              void* d_out, int out_size, void* d_ws, size_t ws_size,
                              hipStream_t stream) {
    const float* x     = (const float*)d_in[0];
    const int*   ei    = (const int*)d_in[1];
    const float* W_in  = (const float*)d_in[2];
    const float* b_in  = (const float*)d_in[3];
    const float* W_c   = (const float*)d_in[4];
    const float* b_c   = (const float*)d_in[5];
    const float* W_out = (const float*)d_in[6];
    const float* b_out = (const float*)d_in[7];

    const int N = in_sizes[0] / 16;
    const int E = in_sizes[1] / 2;
    const int* src = ei;        // edge_index[0]
    const int* dst = ei + E;    // edge_index[1]

    const int NB = (N + 255) >> BIN_SHIFT;   // 391 for N=100000

    float* H    = (float*)d_ws;                  // N*32
    float* A    = H + (size_t)N * D_H;           // N*32
    float* B    = A + (size_t)N * D_H;           // N*32
    float* Srep = B + (size_t)N * D_H;           // NREP*32
    int*   cntG   = (int*)(Srep + NREP * D_H);   // N
    int*   binCnt = cntG + N;                    // NB (<= MAXNB)
    int*   ssrcp  = binCnt + MAXNB;              // N*SLOTS
    unsigned int* ebuf = (unsigned int*)H;       // NB*BIN_CAP (8MB) overlays H:
                                                 // H dead until k_gather1, ebuf
                                                 // dead after k_place.

    float* out = (float*)d_out;

    const int abBlocks = (N + PNPB - 1) / PNPB;  // 1563

    // CSR build (reused by both iterations)
    hipMemsetAsync(binCnt, 0, MAXNB * sizeof(int), stream);
    k_bin<<<SB, 256, 0, stream>>>(src, dst, binCnt, ebuf, E);
    k_place<<<NB, 256, 0, stream>>>(binCnt, ebuf, ssrcp, cntG, N);

    // Iteration 0
    k_ab0<<<abBlocks, 256, 0, stream>>>(x, W_in, b_in, W_c, b_c, A, B, N);
    k_gather1<<<(int)(((size_t)N * 32 + 255) / 256), 256, 0, stream>>>(cntG, ssrcp, A, B, H, N);

    // Iteration 1
    k_ab1<<<abBlocks, 256, 0, stream>>>(H, x, W_c, b_c, A, B, N);
    hipMemsetAsync(Srep, 0, NREP * D_H * sizeof(float), stream);
    k_gather2<<<(N + 7) / 8, 256, 0, stream>>>(cntG, ssrcp, A, B, Srep, N);

    k_final<<<1, 64, 0, stream>>>(Srep, W_out, b_out, out, 1.f / (float)N);
}